// Round 1
// baseline (525.190 us; speedup 1.0000x reference)
//
#include <hip/hip_runtime.h>
#include <hip/hip_bf16.h>

typedef __attribute__((ext_vector_type(8))) short short8;
typedef __attribute__((ext_vector_type(4))) float f32x4;

#define BB 128
#define HHH 16
#define WWW 48
#define DD 512
#define UU 512
#define ROWS_PER_B (HHH * WWW)      /* 768 */
#define MTOT (BB * ROWS_PER_B)      /* 98304 */

__device__ __forceinline__ unsigned short f2bf(float f) {
    unsigned int u = __float_as_uint(f);
    u += 0x7fffu + ((u >> 16) & 1u);          // round-to-nearest-even
    return (unsigned short)(u >> 16);
}

// ---------------- kernel 0: pack W1 (D,U) fp32 -> W1^T (U,D) bf16 -------------
__global__ void pack_w1t_kernel(const float* __restrict__ w1,
                                unsigned short* __restrict__ w1t) {
    __shared__ float tile[32][33];
    const int bx = blockIdx.x, by = blockIdx.y;
    const int tx = threadIdx.x, ty = threadIdx.y;   // 32 x 8
#pragma unroll
    for (int i = 0; i < 32; i += 8)
        tile[ty + i][tx] = w1[(size_t)(by * 32 + ty + i) * UU + bx * 32 + tx];
    __syncthreads();
#pragma unroll
    for (int i = 0; i < 32; i += 8) {
        const int u = bx * 32 + ty + i;
        const int d = by * 32 + tx;
        w1t[(size_t)u * DD + d] = f2bf(tile[tx][ty + i]);
    }
}

// ---------------- kernel 1: dec_proj[b][u] = dec[b]@W2[:,u] + W1_b[u] + W2_b[u]
__global__ __launch_bounds__(256) void dproj_kernel(
        const float* __restrict__ dec, const float* __restrict__ w2,
        const float* __restrict__ w1b, const float* __restrict__ w2b,
        float* __restrict__ dproj) {
    const int b = blockIdx.y;
    const int u = blockIdx.x * 256 + threadIdx.x;
    float acc = 0.f;
#pragma unroll 8
    for (int d = 0; d < DD; ++d)
        acc += dec[b * DD + d] * w2[(size_t)d * UU + u];
    dproj[b * UU + u] = acc + w1b[u] + w2b[u];
}

// ---------------- kernel 2: fused score GEMM -------------------------------
// score[m] = V_b + sum_u V_w[u] * tanh( enc[m]@W1[:,u] + dec_proj[b][u] )
// 64 rows per block, 8 waves = 2 m-halves x 4 u-chunks(128 u each)
__global__ __launch_bounds__(512, 4) void score_kernel(
        const float* __restrict__ enc, const unsigned short* __restrict__ w1t,
        const float* __restrict__ dproj, const float* __restrict__ vw,
        const float* __restrict__ vb, float* __restrict__ score) {
    __shared__ __align__(16) unsigned short lds[64 * DD];   // 64 KB bf16 tile
    __shared__ float slds[4][64];

    const int tid  = threadIdx.x;
    const int lane = tid & 63;
    const int wave = tid >> 6;
    const int mbase = blockIdx.x * 64;
    const int b = mbase / ROWS_PER_B;        // 64 | 768, so single b per tile

    // ---- stage enc tile (64 x 512) fp32 -> bf16 LDS, XOR-swizzled chunks ----
    {
        const int kc = lane;                 // 8-elem chunk within the row
#pragma unroll
        for (int i = 0; i < 8; ++i) {
            const int row = wave + i * 8;
            const float* src = enc + (size_t)(mbase + row) * DD + kc * 8;
            float4 f0 = *(const float4*)src;
            float4 f1 = *(const float4*)(src + 4);
            short8 v;
            unsigned short* pv = (unsigned short*)&v;
            pv[0] = f2bf(f0.x); pv[1] = f2bf(f0.y); pv[2] = f2bf(f0.z); pv[3] = f2bf(f0.w);
            pv[4] = f2bf(f1.x); pv[5] = f2bf(f1.y); pv[6] = f2bf(f1.z); pv[7] = f2bf(f1.w);
            *(short8*)&lds[row * DD + ((kc ^ (row & 7)) << 3)] = v;
        }
    }
    __syncthreads();

    const int mhalf = wave >> 2;             // 0..1 -> rows [mhalf*32, +32)
    const int uc    = wave & 3;              // 0..3 -> u in [uc*128, +128)
    const int lrow  = lane & 15;
    const int kgrp  = lane >> 4;

    f32x4 acc[2][8] = {};

    const int r0 = mhalf * 32 + lrow;
    const int r1 = r0 + 16;
    const unsigned short* bbase = w1t + (size_t)(uc * 128 + lrow) * DD + kgrp * 8;

#pragma unroll 2
    for (int kk = 0; kk < 16; ++kk) {        // K = 512 in steps of 32
        const int k8 = kk * 4 + kgrp;
        short8 a0 = *(const short8*)&lds[r0 * DD + ((k8 ^ (r0 & 7)) << 3)];
        short8 a1 = *(const short8*)&lds[r1 * DD + ((k8 ^ (r1 & 7)) << 3)];
#pragma unroll
        for (int uf = 0; uf < 8; ++uf) {
            short8 bf = *(const short8*)(bbase + (size_t)uf * 16 * DD + kk * 32);
            acc[0][uf] = __builtin_amdgcn_mfma_f32_16x16x32_bf16(a0, bf, acc[0][uf], 0, 0, 0);
            acc[1][uf] = __builtin_amdgcn_mfma_f32_16x16x32_bf16(a1, bf, acc[1][uf], 0, 0, 0);
        }
    }

    // ---- epilogue: + dec_proj, tanh, dot with V_w, reduce over u ----
    float part[8] = {0.f, 0.f, 0.f, 0.f, 0.f, 0.f, 0.f, 0.f};
    const int ubase = uc * 128 + lrow;
#pragma unroll
    for (int uf = 0; uf < 8; ++uf) {
        const int u = ubase + uf * 16;
        const float cadd = dproj[b * UU + u];
        const float vwe  = vw[u];
#pragma unroll
        for (int mf = 0; mf < 2; ++mf) {
#pragma unroll
            for (int j = 0; j < 4; ++j) {
                float x = acc[mf][uf][j] + cadd;
                x = fminf(fmaxf(x, -30.f), 30.f);
                float e = __expf(2.f * x);
                float h = (e - 1.f) / (e + 1.f);     // tanh(x)
                part[mf * 4 + j] += h * vwe;
            }
        }
    }
    // reduce across the 16 lanes sharing the same m-rows (bits 0..3 of lane)
#pragma unroll
    for (int off = 1; off < 16; off <<= 1) {
#pragma unroll
        for (int p = 0; p < 8; ++p) part[p] += __shfl_xor(part[p], off, 64);
    }
    if (lrow == 0) {
#pragma unroll
        for (int mf = 0; mf < 2; ++mf)
#pragma unroll
            for (int j = 0; j < 4; ++j)
                slds[uc][mhalf * 32 + mf * 16 + kgrp * 4 + j] = part[mf * 4 + j];
    }
    __syncthreads();
    if (tid < 64) {
        float s = slds[0][tid] + slds[1][tid] + slds[2][tid] + slds[3][tid] + vb[0];
        score[mbase + tid] = s;
    }
}

// ---------------- kernel 3: softmax over H (axis=1) ------------------------
__global__ void softmax_kernel(const float* __restrict__ score,
                               float* __restrict__ attn) {
    const int g = blockIdx.x * blockDim.x + threadIdx.x;   // (b,w) group
    if (g >= BB * WWW) return;
    const int b = g / WWW, w = g % WWW;
    const float* s = score + b * ROWS_PER_B + w;
    float v[16];
    float m = -1e30f;
#pragma unroll
    for (int h = 0; h < HHH; ++h) { v[h] = s[h * WWW]; m = fmaxf(m, v[h]); }
    float sum = 0.f;
#pragma unroll
    for (int h = 0; h < HHH; ++h) { v[h] = __expf(v[h] - m); sum += v[h]; }
    const float inv = 1.f / sum;
    float* o = attn + b * ROWS_PER_B + w;
#pragma unroll
    for (int h = 0; h < HHH; ++h) o[h * WWW] = v[h] * inv;
}

// ---------------- kernel 4a: context partial sums --------------------------
__global__ __launch_bounds__(512) void ctx_partial_kernel(
        const float* __restrict__ enc, const float* __restrict__ attn,
        float* __restrict__ partial) {
    const int c = blockIdx.x;            // 0..3 : 192-row chunk
    const int b = blockIdx.y;
    const int t = threadIdx.x;
    const int d4 = (t & 127) * 4;
    const int ro = t >> 7;               // 0..3
    float4 acc = {0.f, 0.f, 0.f, 0.f};
    const int rbase = c * 192;
#pragma unroll 4
    for (int i = 0; i < 48; ++i) {
        const int r = rbase + ro + i * 4;
        const float a = attn[b * ROWS_PER_B + r];
        const float4 e = *(const float4*)(enc + ((size_t)(b * ROWS_PER_B + r)) * DD + d4);
        acc.x += a * e.x; acc.y += a * e.y; acc.z += a * e.z; acc.w += a * e.w;
    }
    *(float4*)(partial + ((size_t)((b * 4 + c) * 4 + ro)) * DD + d4) = acc;
}

// ---------------- kernel 4b: reduce 16 partials ----------------------------
__global__ void ctx_reduce_kernel(const float* __restrict__ partial,
                                  float* __restrict__ out) {
    const int q = blockIdx.x * 256 + threadIdx.x;    // quad index, 16384 total
    const int b = q >> 7;
    const int d4 = (q & 127) * 4;
    float4 s = {0.f, 0.f, 0.f, 0.f};
#pragma unroll
    for (int j = 0; j < 16; ++j) {
        const float4 p = *(const float4*)(partial + ((size_t)(b * 16 + j)) * DD + d4);
        s.x += p.x; s.y += p.y; s.z += p.z; s.w += p.w;
    }
    *(float4*)(out + (size_t)b * DD + d4) = s;
}

extern "C" void kernel_launch(void* const* d_in, const int* in_sizes, int n_in,
                              void* d_out, int out_size, void* d_ws, size_t ws_size,
                              hipStream_t stream) {
    const float* dec = (const float*)d_in[0];
    const float* enc = (const float*)d_in[1];
    const float* w1w = (const float*)d_in[2];
    const float* w1b = (const float*)d_in[3];
    const float* w2w = (const float*)d_in[4];
    const float* w2b = (const float*)d_in[5];
    const float* vw  = (const float*)d_in[6];
    const float* vb  = (const float*)d_in[7];

    float* out = (float*)d_out;
    char* ws = (char*)d_ws;
    unsigned short* w1t = (unsigned short*)(ws);                    // 512 KB
    float* dproj   = (float*)(ws + 524288);                         // 256 KB
    float* score   = (float*)(ws + 524288 + 262144);                // 384 KB
    float* partial = (float*)(ws + 524288 + 262144 + 393216);       // 4 MB

    float* ctx  = out;                 // (B, D)     = 65536 floats
    float* attn = out + BB * DD;       // (B,H,W,1)  = 98304 floats

    pack_w1t_kernel<<<dim3(16, 16), dim3(32, 8), 0, stream>>>(w1w, w1t);
    dproj_kernel<<<dim3(2, BB), 256, 0, stream>>>(dec, w2w, w1b, w2b, dproj);
    score_kernel<<<MTOT / 64, 512, 0, stream>>>(enc, w1t, dproj, vw, vb, score);
    softmax_kernel<<<(BB * WWW + 255) / 256, 256, 0, stream>>>(score, attn);
    ctx_partial_kernel<<<dim3(4, BB), 512, 0, stream>>>(enc, attn, partial);
    ctx_reduce_kernel<<<64, 256, 0, stream>>>(partial, ctx);
}

// Round 2
// 409.020 us; speedup vs baseline: 1.2840x; 1.2840x over previous
//
#include <hip/hip_runtime.h>
#include <hip/hip_bf16.h>

typedef __attribute__((ext_vector_type(8))) short short8;
typedef __attribute__((ext_vector_type(4))) float f32x4;
typedef unsigned short ushort;

#define BB 128
#define HHH 16
#define WWW 48
#define DD 512
#define UU 512
#define ROWS_PER_B (HHH * WWW)      /* 768 */
#define MTOT (BB * ROWS_PER_B)      /* 98304 */

__device__ __forceinline__ ushort f2bf(float f) {
    unsigned int u = __float_as_uint(f);
    u += 0x7fffu + ((u >> 16) & 1u);          // round-to-nearest-even
    return (ushort)(u >> 16);
}

__device__ __forceinline__ void gload_lds16(const ushort* g, ushort* l) {
    __builtin_amdgcn_global_load_lds(
        (const __attribute__((address_space(1))) unsigned int*)(const void*)g,
        (__attribute__((address_space(3))) unsigned int*)(void*)l,
        16, 0, 0);
}

// ---------------- kernel 0: pack W1 (D,U) fp32 -> w1p[kc][u][s^(u&7)] bf16 ----
// w1p flat: kc*32768 + u*64 + s'*8 + j  holds  W1[kc*64 + s*8 + j][u]
__global__ __launch_bounds__(256) void pack_w1p_kernel(const float* __restrict__ w1,
                                                       ushort* __restrict__ w1p) {
    __shared__ __align__(16) ushort tile[64 * 72];
    const int t  = threadIdx.x;
    const int u0 = blockIdx.x * 64;
    const int kc = blockIdx.y;               // d-chunk of 64
    const int ul = t & 63;
    const int db = t >> 6;                   // 0..3
#pragma unroll
    for (int i = 0; i < 16; ++i) {
        const int d = db + i * 4;
        tile[ul * 72 + d] = f2bf(w1[(size_t)(kc * 64 + d) * UU + u0 + ul]);
    }
    __syncthreads();
    const int u = t >> 2;                    // 0..63 local
    const int s = (t & 3) * 2;               // 0,2,4,6
    const int x = u & 7;                     // (u0+u)&7 == u&7 since u0%64==0
    short8 v0 = *(const short8*)&tile[u * 72 + s * 8];
    short8 v1 = *(const short8*)&tile[u * 72 + s * 8 + 8];
    *(short8*)&w1p[(size_t)kc * 32768 + (u0 + u) * 64 + (( s      ^ x)) * 8] = v0;
    *(short8*)&w1p[(size_t)kc * 32768 + (u0 + u) * 64 + (((s + 1) ^ x)) * 8] = v1;
}

// ---------------- kernel 1: dec_proj[b][u] = dec[b]@W2[:,u] + W1_b[u] + W2_b[u]
__global__ __launch_bounds__(256) void dproj_kernel(
        const float* __restrict__ dec, const float* __restrict__ w2,
        const float* __restrict__ w1b, const float* __restrict__ w2b,
        float* __restrict__ dproj) {
    const int b = blockIdx.y;
    const int u = blockIdx.x * 256 + threadIdx.x;
    float acc = 0.f;
#pragma unroll 8
    for (int d = 0; d < DD; ++d)
        acc += dec[b * DD + d] * w2[(size_t)d * UU + u];
    dproj[b * UU + u] = acc + w1b[u] + w2b[u];
}

// ---------------- kernel 2: fused score GEMM -------------------------------
// score[m] = V_b + sum_u V_w[u] * tanh( enc[m]@W1[:,u] + dec_proj[b][u] )
// Block: 128 m-rows x 512 u, K-step 64, 8 waves = 2 mh x 4 uc.
__global__ __launch_bounds__(512, 2) void score_kernel(
        const float* __restrict__ enc, const ushort* __restrict__ w1p,
        const float* __restrict__ dproj, const float* __restrict__ vw,
        const float* __restrict__ vb, float* __restrict__ score) {
    __shared__ __align__(16) ushort Bb[2][512 * 64];   // 2 x 64 KB
    __shared__ __align__(16) ushort Ab[128 * 64];      // 16 KB (epilogue scratch reuse)

    const int tid  = threadIdx.x;
    const int lane = tid & 63;
    const int wave = tid >> 6;
    const int mbase = blockIdx.x * 128;
    const int b = mbase / ROWS_PER_B;

    const int mh   = wave >> 2;              // 0..1 -> 64 rows each
    const int uc   = wave & 3;               // 0..3 -> 128 u each
    const int lrow = lane & 15;
    const int kgrp = lane >> 4;

    // A staging mapping: thread -> (row, 16 floats = 2 subchunks)
    const int ar  = tid >> 2;                // 0..127
    const int asp = (tid & 3) * 2;           // s base: 0,2,4,6
    const float* abase = enc + (size_t)(mbase + ar) * DD + asp * 8;
    const int s0p = ( asp      ^ (ar & 7)) * 8;
    const int s1p = ((asp + 1) ^ (ar & 7)) * 8;

    f32x4 acc[4][8] = {};

    // ---- prologue: stage kc = 0 ----
    {
        float4 a0 = ((const float4*)abase)[0];
        float4 a1 = ((const float4*)abase)[1];
        float4 a2 = ((const float4*)abase)[2];
        float4 a3 = ((const float4*)abase)[3];
        const ushort* bsrc = w1p + tid * 8;
#pragma unroll
        for (int i = 0; i < 8; ++i)
            gload_lds16(bsrc + i * 4096, &Bb[0][tid * 8 + i * 4096]);
        short8 w0, w1v;
        ushort* p0 = (ushort*)&w0; ushort* p1 = (ushort*)&w1v;
        p0[0]=f2bf(a0.x); p0[1]=f2bf(a0.y); p0[2]=f2bf(a0.z); p0[3]=f2bf(a0.w);
        p0[4]=f2bf(a1.x); p0[5]=f2bf(a1.y); p0[6]=f2bf(a1.z); p0[7]=f2bf(a1.w);
        p1[0]=f2bf(a2.x); p1[1]=f2bf(a2.y); p1[2]=f2bf(a2.z); p1[3]=f2bf(a2.w);
        p1[4]=f2bf(a3.x); p1[5]=f2bf(a3.y); p1[6]=f2bf(a3.z); p1[7]=f2bf(a3.w);
        *(short8*)&Ab[ar * 64 + s0p] = w0;
        *(short8*)&Ab[ar * 64 + s1p] = w1v;
    }

    int cur = 0;
    for (int kc = 0; kc < 8; ++kc) {
        __syncthreads();                     // staging for kc complete

        float4 a0, a1, a2, a3;
        if (kc < 7) {
            const float* asrc = abase + (kc + 1) * 64;
            a0 = ((const float4*)asrc)[0];
            a1 = ((const float4*)asrc)[1];
            a2 = ((const float4*)asrc)[2];
            a3 = ((const float4*)asrc)[3];
            const ushort* bsrc = w1p + (size_t)(kc + 1) * 32768 + tid * 8;
#pragma unroll
            for (int i = 0; i < 8; ++i)
                gload_lds16(bsrc + i * 4096, &Bb[cur ^ 1][tid * 8 + i * 4096]);
        }

        const ushort* Bc = &Bb[cur][0];
#pragma unroll
        for (int kk = 0; kk < 2; ++kk) {
            const int sub = kk * 4 + kgrp;
            short8 a[4], bf[8];
#pragma unroll
            for (int ms = 0; ms < 4; ++ms) {
                const int r = mh * 64 + ms * 16 + lrow;
                a[ms] = *(const short8*)&Ab[r * 64 + (sub ^ (r & 7)) * 8];
            }
#pragma unroll
            for (int uf = 0; uf < 8; ++uf) {
                const int u = uc * 128 + uf * 16 + lrow;
                bf[uf] = *(const short8*)&Bc[u * 64 + (sub ^ (u & 7)) * 8];
            }
#pragma unroll
            for (int ms = 0; ms < 4; ++ms)
#pragma unroll
                for (int uf = 0; uf < 8; ++uf)
                    acc[ms][uf] = __builtin_amdgcn_mfma_f32_16x16x32_bf16(
                        a[ms], bf[uf], acc[ms][uf], 0, 0, 0);
        }

        __syncthreads();                     // compute done, Ab reusable

        if (kc < 7) {
            short8 w0, w1v;
            ushort* p0 = (ushort*)&w0; ushort* p1 = (ushort*)&w1v;
            p0[0]=f2bf(a0.x); p0[1]=f2bf(a0.y); p0[2]=f2bf(a0.z); p0[3]=f2bf(a0.w);
            p0[4]=f2bf(a1.x); p0[5]=f2bf(a1.y); p0[6]=f2bf(a1.z); p0[7]=f2bf(a1.w);
            p1[0]=f2bf(a2.x); p1[1]=f2bf(a2.y); p1[2]=f2bf(a2.z); p1[3]=f2bf(a2.w);
            p1[4]=f2bf(a3.x); p1[5]=f2bf(a3.y); p1[6]=f2bf(a3.z); p1[7]=f2bf(a3.w);
            *(short8*)&Ab[ar * 64 + s0p] = w0;
            *(short8*)&Ab[ar * 64 + s1p] = w1v;
        }
        cur ^= 1;
    }

    // ---- epilogue: + dec_proj, tanh, dot V_w, reduce ----
    float part[4][4] = {};
#pragma unroll
    for (int uf = 0; uf < 8; ++uf) {
        const int u = uc * 128 + uf * 16 + lrow;
        const float cadd = dproj[b * UU + u];
        const float vwe  = vw[u];
#pragma unroll
        for (int ms = 0; ms < 4; ++ms)
#pragma unroll
            for (int j = 0; j < 4; ++j) {
                float x = acc[ms][uf][j] + cadd;
                x = fminf(fmaxf(x, -15.f), 15.f);
                float e = __expf(2.f * x);
                part[ms][j] += vwe * ((e - 1.f) / (e + 1.f));
            }
    }
#pragma unroll
    for (int off = 1; off < 16; off <<= 1)
#pragma unroll
        for (int ms = 0; ms < 4; ++ms)
#pragma unroll
            for (int j = 0; j < 4; ++j)
                part[ms][j] += __shfl_xor(part[ms][j], off, 64);

    float* scr = (float*)Ab;                 // 4 x 128 floats
    if (lrow == 0) {
#pragma unroll
        for (int ms = 0; ms < 4; ++ms)
#pragma unroll
            for (int j = 0; j < 4; ++j)
                scr[uc * 128 + mh * 64 + ms * 16 + kgrp * 4 + j] = part[ms][j];
    }
    __syncthreads();
    if (tid < 128)
        score[mbase + tid] = scr[tid] + scr[128 + tid] + scr[256 + tid]
                           + scr[384 + tid] + vb[0];
}

// ---------------- kernel 3: softmax over H (axis=1) ------------------------
__global__ void softmax_kernel(const float* __restrict__ score,
                               float* __restrict__ attn) {
    const int g = blockIdx.x * blockDim.x + threadIdx.x;   // (b,w) group
    if (g >= BB * WWW) return;
    const int b = g / WWW, w = g % WWW;
    const float* s = score + b * ROWS_PER_B + w;
    float v[16];
    float m = -1e30f;
#pragma unroll
    for (int h = 0; h < HHH; ++h) { v[h] = s[h * WWW]; m = fmaxf(m, v[h]); }
    float sum = 0.f;
#pragma unroll
    for (int h = 0; h < HHH; ++h) { v[h] = __expf(v[h] - m); sum += v[h]; }
    const float inv = 1.f / sum;
    float* o = attn + b * ROWS_PER_B + w;
#pragma unroll
    for (int h = 0; h < HHH; ++h) o[h * WWW] = v[h] * inv;
}

// ---------------- kernel 4a: context partial sums --------------------------
__global__ __launch_bounds__(512) void ctx_partial_kernel(
        const float* __restrict__ enc, const float* __restrict__ attn,
        float* __restrict__ partial) {
    const int c = blockIdx.x;            // 0..3 : 192-row chunk
    const int b = blockIdx.y;
    const int t = threadIdx.x;
    const int d4 = (t & 127) * 4;
    const int ro = t >> 7;               // 0..3
    float4 acc = {0.f, 0.f, 0.f, 0.f};
    const int rbase = c * 192;
#pragma unroll 8
    for (int i = 0; i < 48; ++i) {
        const int r = rbase + ro + i * 4;
        const float a = attn[b * ROWS_PER_B + r];
        const float4 e = *(const float4*)(enc + ((size_t)(b * ROWS_PER_B + r)) * DD + d4);
        acc.x += a * e.x; acc.y += a * e.y; acc.z += a * e.z; acc.w += a * e.w;
    }
    *(float4*)(partial + ((size_t)((b * 4 + c) * 4 + ro)) * DD + d4) = acc;
}

// ---------------- kernel 4b: reduce 16 partials ----------------------------
__global__ void ctx_reduce_kernel(const float* __restrict__ partial,
                                  float* __restrict__ out) {
    const int q = blockIdx.x * 256 + threadIdx.x;    // quad index, 16384 total
    const int b = q >> 7;
    const int d4 = (q & 127) * 4;
    float4 s = {0.f, 0.f, 0.f, 0.f};
#pragma unroll
    for (int j = 0; j < 16; ++j) {
        const float4 p = *(const float4*)(partial + ((size_t)(b * 16 + j)) * DD + d4);
        s.x += p.x; s.y += p.y; s.z += p.z; s.w += p.w;
    }
    *(float4*)(out + (size_t)b * DD + d4) = s;
}

extern "C" void kernel_launch(void* const* d_in, const int* in_sizes, int n_in,
                              void* d_out, int out_size, void* d_ws, size_t ws_size,
                              hipStream_t stream) {
    const float* dec = (const float*)d_in[0];
    const float* enc = (const float*)d_in[1];
    const float* w1w = (const float*)d_in[2];
    const float* w1b = (const float*)d_in[3];
    const float* w2w = (const float*)d_in[4];
    const float* w2b = (const float*)d_in[5];
    const float* vw  = (const float*)d_in[6];
    const float* vb  = (const float*)d_in[7];

    float* out = (float*)d_out;
    char* ws = (char*)d_ws;
    ushort* w1p    = (ushort*)(ws);                                 // 512 KB
    float* dproj   = (float*)(ws + 524288);                         // 256 KB
    float* score   = (float*)(ws + 524288 + 262144);                // 384 KB
    float* partial = (float*)(ws + 524288 + 262144 + 393216);       // 4 MB

    float* ctx  = out;                 // (B, D)     = 65536 floats
    float* attn = out + BB * DD;       // (B,H,W,1)  = 98304 floats

    pack_w1p_kernel<<<dim3(8, 8), 256, 0, stream>>>(w1w, w1p);
    dproj_kernel<<<dim3(2, BB), 256, 0, stream>>>(dec, w2w, w1b, w2b, dproj);
    score_kernel<<<MTOT / 128, 512, 0, stream>>>(enc, w1p, dproj, vw, vb, score);
    softmax_kernel<<<(BB * WWW + 255) / 256, 256, 0, stream>>>(score, attn);
    ctx_partial_kernel<<<dim3(4, BB), 512, 0, stream>>>(enc, attn, partial);
    ctx_reduce_kernel<<<64, 256, 0, stream>>>(partial, ctx);
}